// Round 17
// baseline (219.300 us; speedup 1.0000x reference)
//
#include <hip/hip_runtime.h>

#define HID 30
#define TS  512
#define NB  16
#define LOG2E 1.44269504088896340736f
#define XSTR 17    // ints per t-row of xs (odd stride)

typedef __attribute__((ext_vector_type(8))) short bf16x8;
typedef __attribute__((ext_vector_type(4))) float f32x4;

__device__ __forceinline__ float rcp_f(float x){ return __builtin_amdgcn_rcpf(x); }
__device__ __forceinline__ float ex2_f(float x){ return __builtin_amdgcn_exp2f(x); }

__global__ __launch_bounds__(512, 4)
void lstm_mfma_u1e(const float* __restrict__ batch,
                   const float* __restrict__ W_ih,
                   const float* __restrict__ W_hh,
                   const float* __restrict__ b_ih,
                   const float* __restrict__ b_hh,
                   const float* __restrict__ W_fc,
                   const float* __restrict__ b_fc,
                   float* __restrict__ out)
{
    __shared__ int xs[TS * XSTR];                      // 34.8 KB packed bf16 hi|lo
    __shared__ __align__(16) short hhi[2][4][NB][8];   // [buf][kgroup][col][slot]
    __shared__ __align__(16) short hlo[2][4][NB][8];   // conflict-free b128 reads

    const int tid  = threadIdx.x;
    const int w    = tid >> 6;        // wave 0..7: owns units 4w..4w+3
    const int lane = tid & 63;
    const int q    = lane >> 4;       // k-quadrant / C-row-quadrant
    const int col  = lane & 15;       // batch col
    const int b0   = blockIdx.x * NB;
    const int u4   = 4 * w + q;       // this lane's unit (30,31 dummy)
    const int g    = u4 >> 3;         // h-buffer group
    const int s    = u4 & 7;          // slot within group

    // ---- stage x, pre-split into packed bf16 (hi | lo<<16)  [r13 verbatim] --
    #pragma unroll 4
    for (int i = 0; i < NB; ++i) {
        const float v = batch[(size_t)(b0 + i) * TS + tid];
        const __bf16 xh = (__bf16)v;
        const __bf16 xl = (__bf16)(v - (float)xh);
        xs[tid * XSTR + i] =
            (int)((unsigned)__builtin_bit_cast(unsigned short, xh) |
                 ((unsigned)__builtin_bit_cast(unsigned short, xl) << 16));
    }
    // ---- zero h buffers ----
    for (int i = tid; i < 2 * 4 * NB * 8 / 2; i += 512) {
        ((int*)hhi)[i] = 0;
        ((int*)hlo)[i] = 0;
    }

    // ---- A fragment: row rho=col -> gate=col&3, unit=4w+(col>>2);
    //      k = 8q+jj; k<30: W_hh, 30: bias, 31: W_ih; prescaled  [r13 verbatim]
    bf16x8 ahi, alo;
    {
        const int gate = col & 3;
        const int unit = 4 * w + (col >> 2);
        const float sG = (gate == 2) ? (-2.0f * LOG2E) : (-LOG2E);
        const int R = gate * HID + unit;
        #pragma unroll
        for (int jj = 0; jj < 8; ++jj) {
            const int kk = q * 8 + jj;
            float wv = 0.0f;
            if (unit < HID) {
                if (kk < HID)      wv = W_hh[R * HID + kk];
                else if (kk == 30) wv = b_ih[R] + b_hh[R];
                else               wv = W_ih[R];
            }
            wv *= sG;
            const __bf16 hi = (__bf16)wv;
            const __bf16 lo = (__bf16)(wv - (float)hi);
            ahi[jj] = (short)__builtin_bit_cast(unsigned short, hi);
            alo[jj] = (short)__builtin_bit_cast(unsigned short, lo);
        }
    }

    __syncthreads();

    const float TWOL = 2.0f * LOG2E;
    float cm = 0.0f;                  // -2L * c for the lane's unit

#define STEP(T, RB, WB)                                                        \
{                                                                              \
    int4 vhi = *(const int4*)&hhi[RB][q][col][0];                              \
    int4 vlo = *(const int4*)&hlo[RB][q][col][0];                              \
    /* read-side override (r13): q==3 lanes replace k=30,31 with 1.0, x(T) */  \
    const unsigned xp = (unsigned)xs[(T) * XSTR + col];                        \
    vhi.w = (q == 3) ? (int)(0x3F80u | (xp << 16)) : vhi.w;                    \
    vlo.w = (q == 3) ? (int)(xp & 0xFFFF0000u)     : vlo.w;                    \
    const bf16x8 bhi = __builtin_bit_cast(bf16x8, vhi);                        \
    const bf16x8 blo = __builtin_bit_cast(bf16x8, vlo);                        \
    const f32x4 z = {0.f, 0.f, 0.f, 0.f};                                      \
    /* depth-2 MFMA: accP = alo.bhi -> +ahi.bhi ; accQ = ahi.blo (parallel) */ \
    f32x4 accP = __builtin_amdgcn_mfma_f32_16x16x32_bf16(alo, bhi, z, 0, 0, 0);\
    f32x4 accQ = __builtin_amdgcn_mfma_f32_16x16x32_bf16(ahi, blo, z, 0, 0, 0);\
    accP = __builtin_amdgcn_mfma_f32_16x16x32_bf16(ahi, bhi, accP, 0, 0, 0);   \
    const float ai = accP[0] + accQ[0];                                        \
    const float af = accP[1] + accQ[1];                                        \
    const float ag = accP[2] + accQ[2];                                        \
    const float ao = accP[3] + accQ[3];                                        \
    const float ei = ex2_f(ai), ef = ex2_f(af);                                \
    const float eg = ex2_f(ag), eo = ex2_f(ao);                                \
    const float P  = (1.0f + ei) * (1.0f + eg);                                \
    const float Q  = 1.0f + ef;                                                \
    const float m1 = (eg - 1.0f) * Q;                                          \
    const float num = fmaf(TWOL, m1, cm * P);                                  \
    cm = num * rcp_f(P * Q);                                                   \
    const float e = ex2_f(cm);                                                 \
    const float h = (1.0f - e) * rcp_f((1.0f + e) * (1.0f + eo));              \
    const __bf16 hh = (__bf16)h;                                               \
    const __bf16 hl = (__bf16)(h - (float)hh);                                 \
    /* unconditional store (r13): dummy units 30,31 land in [3][col][6,7],  */ \
    /* which only q==3 reads -- and those slots get overridden above.       */ \
    hhi[WB][g][col][s] = (short)__builtin_bit_cast(unsigned short, hh);        \
    hlo[WB][g][col][s] = (short)__builtin_bit_cast(unsigned short, hl);        \
    __syncthreads();                                                           \
}

    for (int t2 = 0; t2 < TS / 2; ++t2) {
        STEP(2 * t2,     0, 1)
        STEP(2 * t2 + 1, 1, 0)
    }
#undef STEP

    // ---- final projection: h(T) in buffer 0 ----
    if (tid < NB) {
        float acc = b_fc[0];
        #pragma unroll
        for (int u = 0; u < HID; ++u) {
            const float hv =
                (float)__builtin_bit_cast(__bf16, (unsigned short)hhi[0][u >> 3][tid][u & 7]) +
                (float)__builtin_bit_cast(__bf16, (unsigned short)hlo[0][u >> 3][tid][u & 7]);
            acc = fmaf(hv, W_fc[u], acc);
        }
        out[b0 + tid] = acc;
    }
}

extern "C" void kernel_launch(void* const* d_in, const int* in_sizes, int n_in,
                              void* d_out, int out_size, void* d_ws, size_t ws_size,
                              hipStream_t stream) {
    const float* batch = (const float*)d_in[0];
    const float* W_ih  = (const float*)d_in[1];
    const float* W_hh  = (const float*)d_in[2];
    const float* b_ih  = (const float*)d_in[3];
    const float* b_hh  = (const float*)d_in[4];
    const float* W_fc  = (const float*)d_in[5];
    const float* b_fc  = (const float*)d_in[6];
    float* out = (float*)d_out;

    const int blocks = 8192 / NB;   // 512 blocks x 8 waves = 4096 waves
    lstm_mfma_u1e<<<blocks, 512, 0, stream>>>(batch, W_ih, W_hh, b_ih, b_hh,
                                              W_fc, b_fc, out);
}

// Round 18
// 186.827 us; speedup vs baseline: 1.1738x; 1.1738x over previous
//
#include <hip/hip_runtime.h>

#define HID 30
#define TS  512
#define NB  16
#define LOG2E 1.44269504088896340736f
#define XSTR 17    // ints per t-row of xs (odd stride)
#define HS   40    // shorts per col-row of h buffers (80 B)

typedef __attribute__((ext_vector_type(8))) short bf16x8;
typedef __attribute__((ext_vector_type(4))) float f32x4;

__device__ __forceinline__ float rcp_f(float x){ return __builtin_amdgcn_rcpf(x); }
__device__ __forceinline__ float ex2_f(float x){ return __builtin_amdgcn_exp2f(x); }

__global__ __launch_bounds__(512, 4)
void lstm_mfma_u1(const float* __restrict__ batch,
                  const float* __restrict__ W_ih,
                  const float* __restrict__ W_hh,
                  const float* __restrict__ b_ih,
                  const float* __restrict__ b_hh,
                  const float* __restrict__ W_fc,
                  const float* __restrict__ b_fc,
                  float* __restrict__ out)
{
    __shared__ int xs[TS * XSTR];                    // 34.8 KB, packed bf16 hi|lo
    __shared__ __align__(16) short hhi[2][NB][HS];   // 2.5 KB
    __shared__ __align__(16) short hlo[2][NB][HS];   // 2.5 KB

    const int tid  = threadIdx.x;
    const int w    = tid >> 6;        // wave 0..7: owns units 4w..4w+3
    const int lane = tid & 63;
    const int q    = lane >> 4;       // k-quadrant / C-row-quadrant
    const int col  = lane & 15;       // batch col
    const int b0   = blockIdx.x * NB;

    // ---- stage x, pre-split into packed bf16 (hi | lo<<16) ----
    #pragma unroll 4
    for (int i = 0; i < NB; ++i) {
        const float v = batch[(size_t)(b0 + i) * TS + tid];
        const __bf16 xh = (__bf16)v;
        const __bf16 xl = (__bf16)(v - (float)xh);
        xs[tid * XSTR + i] =
            (int)((unsigned)__builtin_bit_cast(unsigned short, xh) |
                 ((unsigned)__builtin_bit_cast(unsigned short, xl) << 16));
    }
    // ---- zero h buffers ----
    for (int i = tid; i < 2 * NB * HS / 2; i += 512) {
        ((int*)hhi)[i] = 0;
        ((int*)hlo)[i] = 0;
    }

    // ---- A fragment (1 tile/wave): row rho=col -> gate=col&3, unit=4w+(col>>2)
    //      k = 8q+jj; k<30: W_hh, 30: bias, 31: W_ih; prescaled ----
    bf16x8 ahi, alo;
    {
        const int gate = col & 3;
        const int unit = 4 * w + (col >> 2);
        const float sG = (gate == 2) ? (-2.0f * LOG2E) : (-LOG2E);
        const int R = gate * HID + unit;
        #pragma unroll
        for (int jj = 0; jj < 8; ++jj) {
            const int kk = q * 8 + jj;
            float wv = 0.0f;
            if (unit < HID) {
                if (kk < HID)      wv = W_hh[R * HID + kk];
                else if (kk == 30) wv = b_ih[R] + b_hh[R];
                else               wv = W_ih[R];
            }
            wv *= sG;
            const __bf16 hi = (__bf16)wv;
            const __bf16 lo = (__bf16)(wv - (float)hi);
            ahi[jj] = (short)__builtin_bit_cast(unsigned short, hi);
            alo[jj] = (short)__builtin_bit_cast(unsigned short, lo);
        }
    }

    __syncthreads();

    const float TWOL = 2.0f * LOG2E;
    float cm = 0.0f;                  // -2L * c for the lane's unit

#define STEP(T, RB, WB)                                                        \
{                                                                              \
    int4 vhi = *(const int4*)&hhi[RB][col][8 * q];                             \
    int4 vlo = *(const int4*)&hlo[RB][col][8 * q];                             \
    const unsigned xp = (unsigned)xs[(T) * XSTR + col];                        \
    vhi.w = (q == 3) ? (int)(0x3F80u | (xp << 16)) : vhi.w;                    \
    vlo.w = (q == 3) ? (int)(xp & 0xFFFF0000u)     : vlo.w;                    \
    const bf16x8 bhi = __builtin_bit_cast(bf16x8, vhi);                        \
    const bf16x8 blo = __builtin_bit_cast(bf16x8, vlo);                        \
    f32x4 a = {0.f, 0.f, 0.f, 0.f};                                            \
    a = __builtin_amdgcn_mfma_f32_16x16x32_bf16(ahi, bhi, a, 0, 0, 0);         \
    a = __builtin_amdgcn_mfma_f32_16x16x32_bf16(ahi, blo, a, 0, 0, 0);         \
    a = __builtin_amdgcn_mfma_f32_16x16x32_bf16(alo, bhi, a, 0, 0, 0);         \
    /* a = (ai, af, ag, ao) of unit 4w+q, batch col */                         \
    const float ei = ex2_f(a[0]), ef = ex2_f(a[1]);                            \
    const float eg = ex2_f(a[2]), eo = ex2_f(a[3]);                            \
    const float P  = (1.0f + ei) * (1.0f + eg);                                \
    const float Q  = 1.0f + ef;                                                \
    const float m1 = (eg - 1.0f) * Q;                                          \
    const float num = fmaf(TWOL, m1, cm * P);                                  \
    cm = num * rcp_f(P * Q);                                                   \
    const float e = ex2_f(cm);                                                 \
    const float h = (1.0f - e) * rcp_f((1.0f + e) * (1.0f + eo));              \
    const __bf16 hh = (__bf16)h;                                               \
    const __bf16 hl = (__bf16)(h - (float)hh);                                 \
    hhi[WB][col][4 * w + q] = (short)__builtin_bit_cast(unsigned short, hh);   \
    hlo[WB][col][4 * w + q] = (short)__builtin_bit_cast(unsigned short, hl);   \
    __syncthreads();                                                           \
}

    for (int t2 = 0; t2 < TS / 2; ++t2) {
        STEP(2 * t2,     0, 1)
        STEP(2 * t2 + 1, 1, 0)
    }
#undef STEP

    // ---- final projection: h(T) in buffer 0 ----
    if (tid < NB) {
        const short* hh = &hhi[0][tid][0];
        const short* hl = &hlo[0][tid][0];
        float acc = b_fc[0];
        #pragma unroll
        for (int u = 0; u < HID; ++u) {
            const float hv =
                (float)__builtin_bit_cast(__bf16, (unsigned short)hh[u]) +
                (float)__builtin_bit_cast(__bf16, (unsigned short)hl[u]);
            acc = fmaf(hv, W_fc[u], acc);
        }
        out[b0 + tid] = acc;
    }
}

extern "C" void kernel_launch(void* const* d_in, const int* in_sizes, int n_in,
                              void* d_out, int out_size, void* d_ws, size_t ws_size,
                              hipStream_t stream) {
    const float* batch = (const float*)d_in[0];
    const float* W_ih  = (const float*)d_in[1];
    const float* W_hh  = (const float*)d_in[2];
    const float* b_ih  = (const float*)d_in[3];
    const float* b_hh  = (const float*)d_in[4];
    const float* W_fc  = (const float*)d_in[5];
    const float* b_fc  = (const float*)d_in[6];
    float* out = (float*)d_out;

    const int blocks = 8192 / NB;   // 512 blocks x 8 waves = 4096 waves
    lstm_mfma_u1<<<blocks, 512, 0, stream>>>(batch, W_ih, W_hh, b_ih, b_hh,
                                             W_fc, b_fc, out);
}